// Round 2
// baseline (481.203 us; speedup 1.0000x reference)
//
#include <hip/hip_runtime.h>
#include <math.h>

// MLA decode attention (fp32), flash-decoding split over sequence chunks.
// B=64, H=16, latent D=576, V=512, MAX_LEN=4096.
//
// R1 change vs R0: removed the 64 KB LDS V-staging buffer (occupancy was
// 6.9% — 1 block/CU at 104 KB LDS). Phase 3 now re-reads V from global;
// those rows were fetched by phase 1 two barriers earlier, so they hit
// L1/L2. LDS drops to ~39 KB -> 4 blocks/CU (16 waves/CU, which is also
// the VGPR cap at 128 regs via __launch_bounds__(256,4)). nchunk=32 when
// the workspace allows, so early-exit blocks don't drain residency.

namespace {
constexpr int NB = 64;
constexpr int NH = 16;
constexpr int MAXLEN = 4096;
constexpr int D = 576;
constexpr int DV = 512;
constexpr int NF4 = D / 64;   // 9 float4 per lane-slice
constexpr int TR = 32;        // tile rows
constexpr float SCALE = 0.041666666666666664f;
constexpr float NEGINF = -1e30f;
}

__global__ __launch_bounds__(256, 4)
void mla_chunk(const float* __restrict__ qg,
               const float* __restrict__ kvnew,
               const float* __restrict__ cache,
               const int* __restrict__ lens,
               float* __restrict__ ws_o,
               float* __restrict__ ws_ml,
               int nchunk, int chunk)
{
    const int c = blockIdx.x;
    const int b = blockIdx.y;
    const int tid = (int)threadIdx.x;

    const int total = lens[b] + 1;
    const int start = c * chunk;
    if (start >= total) return;           // uniform early-exit, no barriers yet
    const int end = min(start + chunk, total);
    const int newpos = total - 1;

    __shared__ float q_s[NH][D];        // 36864 B
    __shared__ float p_s[TR][NH];       // 2048 B
    __shared__ float scl_s[NH];

    {   // load Q for this batch: 2304 float4, coalesced
        const float4* qsrc = (const float4*)(qg + (size_t)b * NH * D);
        float4* qdst = (float4*)&q_s[0][0];
        #pragma unroll
        for (int i = 0; i < (NH * D / 4) / 256; ++i)
            qdst[tid + 256 * i] = qsrc[tid + 256 * i];
    }
    __syncthreads();

    const int wave = tid >> 6;
    const int lane = tid & 63;
    const int rr = lane >> 4;     // row within 4-row quad
    const int dd = lane & 15;     // d-slice index
    const int h_my = tid >> 4;    // phase-2 role: head
    const int rs = tid & 15;      // phase-2 role: row-slice

    const float* vbase = cache + (size_t)b * MAXLEN * D;
    const float* vnew  = kvnew + (size_t)b * D;

    float acc0[NH], acc1[NH];     // PV accumulators: v = 2*tid, 2*tid+1
    #pragma unroll
    for (int h = 0; h < NH; ++h) { acc0[h] = 0.f; acc1[h] = 0.f; }
    float m_run = NEGINF, l_run = 0.f;

    for (int r0 = start; r0 < end; r0 += TR) {
        // ---- phase 1: scores ----
        #pragma unroll
        for (int pass = 0; pass < 2; ++pass) {
            const int rl = (wave + 4 * pass) * 4 + rr;   // local row 0..31
            const int row = r0 + rl;
            const bool valid = row < end;
            const float* src = (row == newpos)
                ? vnew : (vbase + (size_t)row * D);
            float4 x[NF4];
            #pragma unroll
            for (int j = 0; j < NF4; ++j) {
                if (valid) x[j] = *(const float4*)(src + j * 64 + dd * 4);
                else       x[j] = make_float4(0.f, 0.f, 0.f, 0.f);
            }
            float sa[NH];
            #pragma unroll
            for (int h = 0; h < NH; ++h) {
                const float4* qp = (const float4*)&q_s[h][0];
                float s = 0.f;
                #pragma unroll
                for (int j = 0; j < NF4; ++j) {
                    float4 qv = qp[j * 16 + dd];
                    s = fmaf(x[j].x, qv.x, s);
                    s = fmaf(x[j].y, qv.y, s);
                    s = fmaf(x[j].z, qv.z, s);
                    s = fmaf(x[j].w, qv.w, s);
                }
                sa[h] = s;
            }
            // reduce-scatter butterfly across the 16 d-lanes: after 4 steps
            // lane dd holds the complete dot for head dd. All register
            // indices static (runtime-indexed arrays would spill).
            #pragma unroll
            for (int s = 0; s < 4; ++s) {
                const int m = 1 << s;
                const int bit = (dd >> s) & 1;
                #pragma unroll
                for (int j = 0; j < (NH >> (s + 1)); ++j) {
                    float keep = bit ? sa[2 * j + 1] : sa[2 * j];
                    float send = bit ? sa[2 * j]     : sa[2 * j + 1];
                    sa[j] = keep + __shfl_xor(send, m);
                }
            }
            p_s[rl][dd] = valid ? sa[0] * SCALE : NEGINF;
        }
        __syncthreads();

        // ---- phase 2: per-head online-softmax update ----
        {
            float s0 = p_s[rs][h_my];
            float s1 = p_s[rs + 16][h_my];
            float tm = fmaxf(s0, s1);
            #pragma unroll
            for (int m = 1; m < 16; m <<= 1)
                tm = fmaxf(tm, __shfl_xor(tm, m));
            const float m_new = fmaxf(m_run, tm);
            const float scl = expf(m_run - m_new);
            const float p0 = expf(s0 - m_new);
            const float p1 = expf(s1 - m_new);
            p_s[rs][h_my] = p0;
            p_s[rs + 16][h_my] = p1;
            float ls = p0 + p1;
            #pragma unroll
            for (int m = 1; m < 16; m <<= 1)
                ls += __shfl_xor(ls, m);
            l_run = l_run * scl + ls;
            m_run = m_new;
            if (rs == 0) scl_s[h_my] = scl;
        }
        __syncthreads();

        // ---- phase 2b: rescale accumulators ----
        {
            const float4* sc4 = (const float4*)&scl_s[0];
            float scl[NH];
            #pragma unroll
            for (int g = 0; g < 4; ++g) {
                float4 v = sc4[g];
                scl[4*g+0] = v.x; scl[4*g+1] = v.y;
                scl[4*g+2] = v.z; scl[4*g+3] = v.w;
            }
            #pragma unroll
            for (int h = 0; h < NH; ++h) { acc0[h] *= scl[h]; acc1[h] *= scl[h]; }
        }
        // ---- phase 3: PV, V re-read from global (L1/L2-hot from phase 1) ----
        const int nrl = min(TR, end - r0);
        if (nrl == TR) {
            #pragma unroll 8
            for (int rl = 0; rl < TR; ++rl) {
                const int row = r0 + rl;
                const float* vsrc = (row == newpos)
                    ? vnew : (vbase + (size_t)row * D);
                const float2 x = *(const float2*)(vsrc + 2 * tid);
                const float4* pp = (const float4*)&p_s[rl][0];
                float p[NH];
                #pragma unroll
                for (int g = 0; g < 4; ++g) {
                    float4 v = pp[g];
                    p[4*g+0] = v.x; p[4*g+1] = v.y;
                    p[4*g+2] = v.z; p[4*g+3] = v.w;
                }
                #pragma unroll
                for (int h = 0; h < NH; ++h) {
                    acc0[h] = fmaf(p[h], x.x, acc0[h]);
                    acc1[h] = fmaf(p[h], x.y, acc1[h]);
                }
            }
        } else {
            for (int rl = 0; rl < nrl; ++rl) {
                const int row = r0 + rl;
                const float* vsrc = (row == newpos)
                    ? vnew : (vbase + (size_t)row * D);
                const float2 x = *(const float2*)(vsrc + 2 * tid);
                const float4* pp = (const float4*)&p_s[rl][0];
                float p[NH];
                #pragma unroll
                for (int g = 0; g < 4; ++g) {
                    float4 v = pp[g];
                    p[4*g+0] = v.x; p[4*g+1] = v.y;
                    p[4*g+2] = v.z; p[4*g+3] = v.w;
                }
                #pragma unroll
                for (int h = 0; h < NH; ++h) {
                    acc0[h] = fmaf(p[h], x.x, acc0[h]);
                    acc1[h] = fmaf(p[h], x.y, acc1[h]);
                }
            }
        }
        __syncthreads();
    }

    // ---- write partial results ----
    const size_t obase = (((size_t)b * nchunk + c) * NH) * (size_t)DV;
    #pragma unroll
    for (int h = 0; h < NH; ++h) {
        *(float2*)&ws_o[obase + (size_t)h * DV + 2 * tid] =
            make_float2(acc0[h], acc1[h]);
    }
    if (rs == 0) {
        const size_t mlb = (((size_t)b * nchunk + c) * NH + h_my) * 2;
        ws_ml[mlb + 0] = m_run;
        ws_ml[mlb + 1] = l_run;
    }
}

__global__ __launch_bounds__(256)
void mla_reduce(const int* __restrict__ lens,
                const float* __restrict__ ws_o,
                const float* __restrict__ ws_ml,
                float* __restrict__ out,
                int nchunk, int chunk)
{
    const int h = blockIdx.x;
    const int b = blockIdx.y;
    const int tid = (int)threadIdx.x;
    const int total = lens[b] + 1;
    const int nact = min(nchunk, (total + chunk - 1) / chunk);

    float M = NEGINF;
    for (int c = 0; c < nact; ++c)
        M = fmaxf(M, ws_ml[(((size_t)b * nchunk + c) * NH + h) * 2]);

    float a0 = 0.f, a1 = 0.f, L = 0.f;
    for (int c = 0; c < nact; ++c) {
        const size_t mlb = (((size_t)b * nchunk + c) * NH + h) * 2;
        const float w = expf(ws_ml[mlb] - M);
        L += w * ws_ml[mlb + 1];
        const float2 o = *(const float2*)&ws_o[
            (((size_t)b * nchunk + c) * NH + h) * (size_t)DV + 2 * tid];
        a0 = fmaf(w, o.x, a0);
        a1 = fmaf(w, o.y, a1);
    }
    const float inv = 1.f / L;
    *(float2*)&out[((size_t)b * NH + h) * (size_t)DV + 2 * tid] =
        make_float2(a0 * inv, a1 * inv);
}

extern "C" void kernel_launch(void* const* d_in, const int* in_sizes, int n_in,
                              void* d_out, int out_size, void* d_ws, size_t ws_size,
                              hipStream_t stream)
{
    (void)in_sizes; (void)n_in; (void)out_size;
    const float* qg    = (const float*)d_in[0];   // [B,H,576]
    const float* kvnew = (const float*)d_in[1];   // [B,1,576]
    const float* cache = (const float*)d_in[2];   // [B,4096,576]
    const int*   lens  = (const int*)d_in[3];     // [B]
    float* out = (float*)d_out;                   // [B,H,512] fp32

    // pick largest chunk split that fits the workspace (67 MB at nchunk=32)
    int nchunk = 32;
    while (nchunk > 1 &&
           (size_t)NB * nchunk * NH * (DV + 2) * sizeof(float) > ws_size)
        nchunk >>= 1;
    const int chunk = MAXLEN / nchunk;

    float* ws_o  = (float*)d_ws;
    float* ws_ml = ws_o + (size_t)NB * nchunk * NH * DV;

    dim3 gA(nchunk, NB);
    mla_chunk<<<gA, 256, 0, stream>>>(qg, kvnew, cache, lens, ws_o, ws_ml,
                                      nchunk, chunk);
    dim3 gB(NH, NB);
    mla_reduce<<<gB, 256, 0, stream>>>(lens, ws_o, ws_ml, out, nchunk, chunk);
}

// Round 3
// 223.985 us; speedup vs baseline: 2.1484x; 2.1484x over previous
//
#include <hip/hip_runtime.h>
#include <math.h>

// MLA decode attention (fp32), flash-decoding split over sequence chunks.
// B=64, H=16, latent D=576, V=512, MAX_LEN=4096.
//
// R2 restructure: wave-per-headgroup.
//  - Block = 256 threads (4 waves), grid (nchunk=32, B). Wave w owns heads
//    w*4..w*4+3; lane = hl*16+dd: head hl, d-slice dd.
//  - Per 16-row tile: K/V rows staged to LDS ONCE via global_load_lds
//    (36864 B, 9x 4KB slices, rows contiguous in cache); the new token's
//    row is overwritten from key_value_states in LDS (input cache never
//    mutated).
//  - Q lives in registers (9 float4/lane). Score: 36 FMA on the dd-slice +
//    4-step butterfly over the 16-lane group -> every lane holds s(head,row).
//  - Softmax state (m,l) is group-uniform in registers: NO barriers, no LDS.
//    Defer-max (THR=8): acc rescale only when the running max grows.
//  - PV: the V-part ds_read_b128s are RETAINED in registers (xv[8]) -> PV is
//    32 reg-reg FMA; V is read exactly once from HBM, once from LDS.
//  - R1 lesson: no launch_bounds min-waves clamp, no unroll-8 (VGPR=64 spill
//    produced 645 MB scratch writes). Target ~120 VGPR, LDS 36.9 KB.

namespace {
constexpr int NH = 16;
constexpr int MAXLEN = 4096;
constexpr int D = 576;
constexpr int DV = 512;
constexpr int TR = 16;        // tile rows; LDS tile = TR*D*4 = 36864 B
constexpr float SCALE_LOG2E = 0.041666666666666664f * 1.4426950408889634f;
constexpr float NEGINF = -1e30f;
constexpr float THR2 = 8.0f;  // defer-max threshold (log2 domain)
}

__device__ __forceinline__ void gload_lds16(const void* g, void* l) {
    __builtin_amdgcn_global_load_lds(
        (const __attribute__((address_space(1))) void*)g,
        (__attribute__((address_space(3))) void*)l, 16, 0, 0);
}

__global__ __launch_bounds__(256)
void mla_chunk(const float* __restrict__ qg,
               const float* __restrict__ kvnew,
               const float* __restrict__ cache,
               const int* __restrict__ lens,
               float* __restrict__ ws_o,
               float* __restrict__ ws_ml,
               int nchunk, int chunk)
{
    const int c = blockIdx.x;
    const int b = blockIdx.y;
    const int tid = (int)threadIdx.x;

    const int total = lens[b] + 1;
    const int start = c * chunk;
    if (start >= total) return;          // uniform early-exit before barriers
    const int end = min(start + chunk, total);
    const int newpos = total - 1;

    __shared__ float kv_s[TR][D];        // 36864 B

    const int wave = tid >> 6;
    const int lane = tid & 63;
    const int hl = lane >> 4;            // head within wave's group of 4
    const int dd = lane & 15;            // d-slice
    const int head = wave * 4 + hl;

    // Q into registers: head's dd-slice, 9 float4 (coalesced per 16-lane grp)
    float4 q[9];
    {
        const float* qp = qg + ((size_t)b * NH + head) * D + dd * 4;
        #pragma unroll
        for (int j = 0; j < 9; ++j)
            q[j] = *(const float4*)(qp + j * 64);
    }

    float4 acc[8];
    #pragma unroll
    for (int j = 0; j < 8; ++j) acc[j] = make_float4(0.f, 0.f, 0.f, 0.f);
    float m2 = NEGINF, l = 0.f;

    for (int r0 = start; r0 < end; r0 += TR) {
        const int nrows = min(TR, end - r0);
        // ---- stage 16 rows -> LDS (rows r0..r0+15 always in-bounds of the
        //      4096-row cache; rows beyond `end` are staged but never read)
        {
            const char* src = (const char*)(cache + ((size_t)b * MAXLEN + r0) * D);
            char* dst = (char*)&kv_s[0][0];
            const int o = tid * 16;
            #pragma unroll
            for (int it = 0; it < 9; ++it)
                gload_lds16(src + it * 4096 + o, dst + it * 4096 + o);
        }
        __syncthreads();                 // compiler drains vmcnt before barrier
        if (newpos >= r0 && newpos < r0 + TR) {   // block-uniform condition
            if (tid < D / 4)
                ((float4*)&kv_s[newpos - r0][0])[tid] =
                    ((const float4*)(kvnew + (size_t)b * D))[tid];
            __syncthreads();
        }

        // ---- per-row: score + online softmax + PV, no barriers ----
        for (int r = 0; r < nrows; ++r) {
            const float* krow = &kv_s[r][0];
            float4 xv[8];
            float s = 0.f;
            #pragma unroll
            for (int j = 0; j < 8; ++j) {
                const float4 x = *(const float4*)(krow + j * 64 + dd * 4);
                xv[j] = x;
                s = fmaf(x.x, q[j].x, s);
                s = fmaf(x.y, q[j].y, s);
                s = fmaf(x.z, q[j].z, s);
                s = fmaf(x.w, q[j].w, s);
            }
            {   // rope part (d 512..575): score only, not retained
                const float4 x = *(const float4*)(krow + DV + dd * 4);
                s = fmaf(x.x, q[8].x, s);
                s = fmaf(x.y, q[8].y, s);
                s = fmaf(x.z, q[8].z, s);
                s = fmaf(x.w, q[8].w, s);
            }
            // butterfly over the 16-lane dd-group: all lanes get full dot
            s += __shfl_xor(s, 1);
            s += __shfl_xor(s, 2);
            s += __shfl_xor(s, 4);
            s += __shfl_xor(s, 8);
            s *= SCALE_LOG2E;            // log2-domain score

            float p;
            if (s > m2 + THR2) {         // rare: rescale accumulators
                const float scl = exp2f(m2 - s);
                m2 = s;
                l *= scl;
                #pragma unroll
                for (int j = 0; j < 8; ++j) {
                    acc[j].x *= scl; acc[j].y *= scl;
                    acc[j].z *= scl; acc[j].w *= scl;
                }
                p = 1.f;
            } else {
                p = exp2f(s - m2);       // bounded by 2^THR2
            }
            l += p;
            #pragma unroll
            for (int j = 0; j < 8; ++j) {
                acc[j].x = fmaf(p, xv[j].x, acc[j].x);
                acc[j].y = fmaf(p, xv[j].y, acc[j].y);
                acc[j].z = fmaf(p, xv[j].z, acc[j].z);
                acc[j].w = fmaf(p, xv[j].w, acc[j].w);
            }
        }
        __syncthreads();                 // protect kv_s before next stage
    }

    // ---- write partials: lane owns dims {j*64+dd*4..+3} of its head ----
    float* op = ws_o + (((size_t)b * nchunk + c) * NH + head) * DV + dd * 4;
    #pragma unroll
    for (int j = 0; j < 8; ++j)
        *(float4*)(op + j * 64) = acc[j];
    if (dd == 0) {
        const size_t mlb = (((size_t)b * nchunk + c) * NH + head) * 2;
        ws_ml[mlb]     = m2;             // log2-domain running max
        ws_ml[mlb + 1] = l;
    }
}

__global__ __launch_bounds__(256)
void mla_reduce(const int* __restrict__ lens,
                const float* __restrict__ ws_o,
                const float* __restrict__ ws_ml,
                float* __restrict__ out,
                int nchunk, int chunk)
{
    const int h = blockIdx.x;
    const int b = blockIdx.y;
    const int tid = (int)threadIdx.x;
    const int total = lens[b] + 1;
    const int nact = min(nchunk, (total + chunk - 1) / chunk);

    float M = NEGINF;
    for (int c = 0; c < nact; ++c)
        M = fmaxf(M, ws_ml[(((size_t)b * nchunk + c) * NH + h) * 2]);

    float a0 = 0.f, a1 = 0.f, L = 0.f;
    for (int c = 0; c < nact; ++c) {
        const size_t mlb = (((size_t)b * nchunk + c) * NH + h) * 2;
        const float w = exp2f(ws_ml[mlb] - M);   // log2-domain merge
        L += w * ws_ml[mlb + 1];
        const float2 o = *(const float2*)&ws_o[
            (((size_t)b * nchunk + c) * NH + h) * (size_t)DV + 2 * tid];
        a0 = fmaf(w, o.x, a0);
        a1 = fmaf(w, o.y, a1);
    }
    const float inv = 1.f / L;
    *(float2*)&out[((size_t)b * NH + h) * (size_t)DV + 2 * tid] =
        make_float2(a0 * inv, a1 * inv);
}

extern "C" void kernel_launch(void* const* d_in, const int* in_sizes, int n_in,
                              void* d_out, int out_size, void* d_ws, size_t ws_size,
                              hipStream_t stream)
{
    (void)in_sizes; (void)n_in; (void)out_size;
    const float* qg    = (const float*)d_in[0];   // [B,H,576]
    const float* kvnew = (const float*)d_in[1];   // [B,1,576]
    const float* cache = (const float*)d_in[2];   // [B,4096,576]
    const int*   lens  = (const int*)d_in[3];     // [B]
    float* out = (float*)d_out;                   // [B,H,512] fp32
    const int NB = 64;

    // largest chunk split that fits the workspace (67 MB at nchunk=32)
    int nchunk = 32;
    while (nchunk > 1 &&
           (size_t)NB * nchunk * NH * (DV + 2) * sizeof(float) > ws_size)
        nchunk >>= 1;
    const int chunk = MAXLEN / nchunk;

    float* ws_o  = (float*)d_ws;
    float* ws_ml = ws_o + (size_t)NB * nchunk * NH * DV;

    dim3 gA(nchunk, NB);
    mla_chunk<<<gA, 256, 0, stream>>>(qg, kvnew, cache, lens, ws_o, ws_ml,
                                      nchunk, chunk);
    dim3 gB(NH, NB);
    mla_reduce<<<gB, 256, 0, stream>>>(lens, ws_o, ws_ml, out, nchunk, chunk);
}